// Round 1
// baseline (13003.659 us; speedup 1.0000x reference)
//
#include <hip/hip_runtime.h>
#include <hip/hip_bf16.h>
#include <math.h>

#define B_ 128
#define S_ 100
#define W_ 20
#define D_ 192
#define L_ 6
#define H_ 8
#define DFF_ 256
#define DH_ 24
#define BS_ (B_*S_)
#define THREED_ 576

// ---------------------------------------------------------------------------
// Kernel 1: per-(b,s) encoder. Fuses embedding gathers, spatial MLP, wfuse,
// window average, mouse/kbd/activity fusion, positional encoding.
// block = 128 threads, grid = B*S.
// ---------------------------------------------------------------------------
__global__ void encode_kernel(
    const int* __restrict__ title_idx, const int* __restrict__ class_idx,
    const int* __restrict__ process_idx, const int* __restrict__ activity_type,
    const float* __restrict__ mouse_pos, const float* __restrict__ rect,
    const float* __restrict__ flags, const float* __restrict__ keyboard_active,
    const float* __restrict__ window_mask,
    const float* __restrict__ title_emb, const float* __restrict__ class_emb,
    const float* __restrict__ process_emb,
    const float* __restrict__ sw1, const float* __restrict__ sb1,
    const float* __restrict__ sw2, const float* __restrict__ sb2,
    const float* __restrict__ wfw, const float* __restrict__ wfb,
    const float* __restrict__ mw1, const float* __restrict__ mb1,
    const float* __restrict__ mw2, const float* __restrict__ mb2,
    const float* __restrict__ act_emb, const float* __restrict__ kbw,
    const float* __restrict__ kbb,
    const float* __restrict__ afw, const float* __restrict__ afb,
    float* __restrict__ x)
{
  int bs = blockIdx.x;            // b*S + s
  int s  = bs % S_;
  int tid = threadIdx.x;          // 0..127

  __shared__ float wcomb[128];
  __shared__ float hid64[64];
  __shared__ float spin[8];

  float avg = 0.f;                // thread owns channel `tid` of avg_w

  for (int w = 0; w < W_; ++w) {
    int base = bs * W_ + w;
    if (tid < 32)       wcomb[tid] = title_emb[title_idx[base] * 32 + tid];
    else if (tid < 64)  wcomb[tid] = class_emb[class_idx[base] * 32 + (tid - 32)];
    else if (tid < 96)  wcomb[tid] = process_emb[process_idx[base] * 32 + (tid - 64)];
    if (tid < 4)        spin[tid] = rect[base * 4 + tid];
    else if (tid < 6)   spin[tid] = flags[base * 2 + (tid - 4)];
    __syncthreads();
    if (tid < 64) {
      float a = sb1[tid];
      #pragma unroll
      for (int k = 0; k < 6; ++k) a += sw1[tid * 6 + k] * spin[k];
      hid64[tid] = fmaxf(a, 0.f);
    }
    __syncthreads();
    if (tid < 32) {
      float a = sb2[tid];
      #pragma unroll
      for (int k = 0; k < 64; ++k) a += sw2[tid * 64 + k] * hid64[k];
      wcomb[96 + tid] = a;
    }
    __syncthreads();
    {
      float a = wfb[tid];
      const float* wr = wfw + tid * 128;
      #pragma unroll 8
      for (int k = 0; k < 128; ++k) a += wr[k] * wcomb[k];
      avg += fmaxf(a, 0.f) * window_mask[base];
    }
    __syncthreads();   // before next w overwrites wcomb
  }
  avg *= (1.f / (float)W_);

  // activity-fusion branch
  __shared__ float cat64[64];
  __shared__ float mh[32];
  __shared__ float af[64];
  if (tid < 32) {
    float mx = mouse_pos[bs * 2 + 0] * (1.f / 1920.f);
    float my = mouse_pos[bs * 2 + 1] * (1.f / 1080.f);
    mh[tid] = fmaxf(mw1[tid * 2 + 0] * mx + mw1[tid * 2 + 1] * my + mb1[tid], 0.f);
  }
  __syncthreads();
  if (tid < 32) {
    float a = mb2[tid];
    #pragma unroll
    for (int k = 0; k < 32; ++k) a += mw2[tid * 32 + k] * mh[k];
    cat64[tid] = a;                                  // no relu on mf output
  } else if (tid < 48) {
    cat64[tid] = act_emb[activity_type[bs] * 16 + (tid - 32)];
  } else if (tid < 64) {
    int j = tid - 48;
    cat64[tid] = kbw[j] * keyboard_active[bs] + kbb[j];
  }
  __syncthreads();
  if (tid < 64) {
    float a = afb[tid];
    #pragma unroll
    for (int k = 0; k < 64; ++k) a += afw[tid * 64 + k] * cat64[k];
    af[tid] = fmaxf(a, 0.f);
  }
  __syncthreads();

  // x = concat(avg_w, af) + pos_encoding(s, :)
  {
    int c = tid;
    float freq = expf(-logf(10000.f) * (float)(2 * (c >> 1)) / (float)D_);
    float ang = (float)s * freq;
    x[(size_t)bs * D_ + c] = avg + ((c & 1) ? cosf(ang) : sinf(ang));
  }
  if (tid < 64) {
    int c = 128 + tid;
    float freq = expf(-logf(10000.f) * (float)(2 * (c >> 1)) / (float)D_);
    float ang = (float)s * freq;
    x[(size_t)bs * D_ + c] = af[tid] + ((c & 1) ? cosf(ang) : sinf(ang));
  }
}

// ---------------------------------------------------------------------------
// Row-per-block GEMM: out(BS, N) = h(BS, K=192) @ w(N, 192)^T + bias, N threads.
// Used for qkv (N=576).
// ---------------------------------------------------------------------------
__global__ void qkv_kernel(const float* __restrict__ h, const float* __restrict__ w,
                           const float* __restrict__ bias, float* __restrict__ out)
{
  int bs = blockIdx.x;
  int tid = threadIdx.x;   // 0..575
  __shared__ float sh[D_];
  if (tid < D_) sh[tid] = h[(size_t)bs * D_ + tid];
  __syncthreads();
  float a = bias[tid];
  const float* wr = w + (size_t)tid * D_;
  #pragma unroll 8
  for (int k = 0; k < D_; ++k) a += wr[k] * sh[k];
  out[(size_t)bs * THREED_ + tid] = a;
}

// ---------------------------------------------------------------------------
// Attention: one block per (b, h, q), 128 threads.
// qkv row layout: [0:192]=q, [192:384]=k, [384:576]=v ; head h slice = h*24.
// ---------------------------------------------------------------------------
__global__ void attn_kernel(const float* __restrict__ qkv, float* __restrict__ o)
{
  int idx = blockIdx.x;
  int q = idx % S_;
  int bh = idx / S_;
  int hh = bh % H_;
  int b = bh / H_;
  int tid = threadIdx.x;

  const float scale = 0.20412414523193154f;  // 1/sqrt(24)

  __shared__ float qv[DH_];
  __shared__ float prob[128];
  __shared__ float red[128];

  const float* qrow = qkv + ((size_t)(b * S_ + q)) * THREED_ + hh * DH_;
  if (tid < DH_) qv[tid] = qrow[tid];
  __syncthreads();

  float score = -1e30f;
  if (tid < S_) {
    const float* krow = qkv + ((size_t)(b * S_ + tid)) * THREED_ + D_ + hh * DH_;
    float a = 0.f;
    #pragma unroll
    for (int d = 0; d < DH_; ++d) a += qv[d] * krow[d];
    score = a * scale;
  }
  red[tid] = score;
  __syncthreads();
  for (int st = 64; st > 0; st >>= 1) {
    if (tid < st) red[tid] = fmaxf(red[tid], red[tid + st]);
    __syncthreads();
  }
  float mx = red[0];
  __syncthreads();
  float e = (tid < S_) ? expf(score - mx) : 0.f;
  prob[tid] = e;
  red[tid] = e;
  __syncthreads();
  for (int st = 64; st > 0; st >>= 1) {
    if (tid < st) red[tid] += red[tid + st];
    __syncthreads();
  }
  float inv_denom = 1.f / red[0];
  __syncthreads();

  if (tid < DH_) {
    float a = 0.f;
    const float* vbase = qkv + (size_t)b * S_ * THREED_ + 2 * D_ + hh * DH_ + tid;
    for (int k = 0; k < S_; ++k) a += prob[k] * vbase[(size_t)k * THREED_];
    o[((size_t)(b * S_ + q)) * D_ + hh * DH_ + tid] = a * inv_denom;
  }
}

// ---------------------------------------------------------------------------
// Fused proj + residual + LayerNorm (in-place on h). 192 threads per block.
// h[c] = LN( h[c] + sum_k w[c,k]*inp[k] + bias[c] ) * g + b
// ---------------------------------------------------------------------------
template <int K>
__global__ void proj_residual_ln_kernel(
    float* __restrict__ h, const float* __restrict__ inp,
    const float* __restrict__ w, const float* __restrict__ bias,
    const float* __restrict__ g, const float* __restrict__ bvec)
{
  int bs = blockIdx.x;
  int tid = threadIdx.x;   // 0..191
  __shared__ float sh[K];
  __shared__ float red[D_];
  __shared__ float stats[2];
  for (int k = tid; k < K; k += D_) sh[k] = inp[(size_t)bs * K + k];
  __syncthreads();
  float a = bias[tid];
  const float* wr = w + (size_t)tid * K;
  #pragma unroll 8
  for (int k = 0; k < K; ++k) a += wr[k] * sh[k];
  float val = h[(size_t)bs * D_ + tid] + a;

  red[tid] = val;
  __syncthreads();
  for (int st = 96; st >= 3; st >>= 1) {
    if (tid < st) red[tid] += red[tid + st];
    __syncthreads();
  }
  if (tid == 0) stats[0] = (red[0] + red[1] + red[2]) * (1.f / (float)D_);
  __syncthreads();
  float m = stats[0];
  float dv = val - m;
  red[tid] = dv * dv;
  __syncthreads();
  for (int st = 96; st >= 3; st >>= 1) {
    if (tid < st) red[tid] += red[tid + st];
    __syncthreads();
  }
  if (tid == 0) stats[1] = (red[0] + red[1] + red[2]) * (1.f / (float)D_);
  __syncthreads();
  float inv = rsqrtf(stats[1] + 1e-5f);
  h[(size_t)bs * D_ + tid] = dv * inv * g[tid] + bvec[tid];
}

// ---------------------------------------------------------------------------
// FF1: ffh(BS,256) = relu(h(BS,192) @ w(256,192)^T + b). 256 threads/block.
// ---------------------------------------------------------------------------
__global__ void ff1_kernel(const float* __restrict__ h, const float* __restrict__ w,
                           const float* __restrict__ b, float* __restrict__ out)
{
  int bs = blockIdx.x;
  int tid = threadIdx.x;   // 0..255
  __shared__ float sh[D_];
  if (tid < D_) sh[tid] = h[(size_t)bs * D_ + tid];
  __syncthreads();
  float a = b[tid];
  const float* wr = w + (size_t)tid * D_;
  #pragma unroll 8
  for (int k = 0; k < D_; ++k) a += wr[k] * sh[k];
  out[(size_t)bs * DFF_ + tid] = fmaxf(a, 0.f);
}

// ---------------------------------------------------------------------------
// Head: one block per (w, b) slot, 256 threads.
// ---------------------------------------------------------------------------
__global__ void head_kernel(const float* __restrict__ x, const float* __restrict__ noise,
                            const float* __restrict__ pw1, const float* __restrict__ pb1,
                            const float* __restrict__ pw2, const float* __restrict__ pb2,
                            const float* __restrict__ ew1, const float* __restrict__ eb1,
                            const float* __restrict__ ew2, const float* __restrict__ eb2,
                            float* __restrict__ out)
{
  int idx = blockIdx.x;     // w*B + b
  int b = idx % B_;
  int w = idx / B_;
  int tid = threadIdx.x;    // 0..255

  __shared__ float slot[D_];
  __shared__ float ph[256];
  __shared__ float eh[128];
  if (tid < D_)
    slot[tid] = x[((size_t)b * S_ + (S_ - 1)) * D_ + tid]
              + noise[((size_t)w * B_ + b) * D_ + tid] * 0.1f;
  __syncthreads();
  {
    float a = pb1[tid];
    const float* wr = pw1 + (size_t)tid * D_;
    #pragma unroll 8
    for (int k = 0; k < D_; ++k) a += wr[k] * slot[k];
    ph[tid] = fmaxf(a, 0.f);
  }
  if (tid < 128) {
    float a = eb1[tid];
    const float* wr = ew1 + (size_t)tid * D_;
    #pragma unroll 8
    for (int k = 0; k < D_; ++k) a += wr[k] * slot[k];
    eh[tid] = fmaxf(a, 0.f);
  }
  __syncthreads();
  if (tid < 4) {
    float a = pb2[tid];
    for (int k = 0; k < 256; ++k) a += pw2[tid * 256 + k] * ph[k];
    out[((size_t)b * W_ + w) * 4 + tid] = a;
  }
  if (tid == 4) {
    float a = eb2[0];
    for (int k = 0; k < 128; ++k) a += ew2[k] * eh[k];
    out[(size_t)B_ * W_ * 4 + (size_t)b * W_ + w] = 1.f / (1.f + expf(-a));
  }
}

// ---------------------------------------------------------------------------
extern "C" void kernel_launch(void* const* d_in, const int* in_sizes, int n_in,
                              void* d_out, int out_size, void* d_ws, size_t ws_size,
                              hipStream_t stream)
{
  const int*   title_idx       = (const int*)  d_in[0];
  const int*   class_idx       = (const int*)  d_in[1];
  const int*   process_idx     = (const int*)  d_in[2];
  const int*   activity_type   = (const int*)  d_in[3];
  const float* mouse_pos       = (const float*)d_in[4];
  const float* rect            = (const float*)d_in[5];
  const float* flags           = (const float*)d_in[6];
  const float* keyboard_active = (const float*)d_in[7];
  const float* window_mask     = (const float*)d_in[8];
  const float* noise           = (const float*)d_in[9];
  const float* title_emb       = (const float*)d_in[10];
  const float* class_emb       = (const float*)d_in[11];
  const float* process_emb     = (const float*)d_in[12];
  const float* spatial_w1      = (const float*)d_in[13];
  const float* spatial_b1      = (const float*)d_in[14];
  const float* spatial_w2      = (const float*)d_in[15];
  const float* spatial_b2      = (const float*)d_in[16];
  const float* wfuse_w         = (const float*)d_in[17];
  const float* wfuse_b         = (const float*)d_in[18];
  const float* mouse_w1        = (const float*)d_in[19];
  const float* mouse_b1        = (const float*)d_in[20];
  const float* mouse_w2        = (const float*)d_in[21];
  const float* mouse_b2        = (const float*)d_in[22];
  const float* act_emb         = (const float*)d_in[23];
  const float* kbd_w           = (const float*)d_in[24];
  const float* kbd_b           = (const float*)d_in[25];
  const float* afuse_w         = (const float*)d_in[26];
  const float* afuse_b         = (const float*)d_in[27];
  const float* qkv_w           = (const float*)d_in[28];
  const float* qkv_b           = (const float*)d_in[29];
  const float* out_w           = (const float*)d_in[30];
  const float* out_b           = (const float*)d_in[31];
  const float* ff1_w           = (const float*)d_in[32];
  const float* ff1_b           = (const float*)d_in[33];
  const float* ff2_w           = (const float*)d_in[34];
  const float* ff2_b           = (const float*)d_in[35];
  const float* ln1_g           = (const float*)d_in[36];
  const float* ln1_b           = (const float*)d_in[37];
  const float* ln2_g           = (const float*)d_in[38];
  const float* ln2_b           = (const float*)d_in[39];
  const float* proj_w1         = (const float*)d_in[40];
  const float* proj_b1         = (const float*)d_in[41];
  const float* proj_w2         = (const float*)d_in[42];
  const float* proj_b2         = (const float*)d_in[43];
  const float* ex_w1           = (const float*)d_in[44];
  const float* ex_b1           = (const float*)d_in[45];
  const float* ex_w2           = (const float*)d_in[46];
  const float* ex_b2           = (const float*)d_in[47];

  float* out = (float*)d_out;

  // workspace layout (floats)
  float* ws   = (float*)d_ws;
  float* x    = ws;                                  // BS*192   = 2,457,600
  float* qkv  = x   + (size_t)BS_ * D_;              // BS*576   = 7,372,800
  float* o    = qkv + (size_t)BS_ * THREED_;         // BS*192
  float* ffh  = o   + (size_t)BS_ * D_;              // BS*256
  (void)ws_size; (void)n_in; (void)in_sizes; (void)out_size;

  // 1. encoder
  encode_kernel<<<BS_, 128, 0, stream>>>(
      title_idx, class_idx, process_idx, activity_type, mouse_pos, rect, flags,
      keyboard_active, window_mask, title_emb, class_emb, process_emb,
      spatial_w1, spatial_b1, spatial_w2, spatial_b2, wfuse_w, wfuse_b,
      mouse_w1, mouse_b1, mouse_w2, mouse_b2, act_emb, kbd_w, kbd_b,
      afuse_w, afuse_b, x);

  // 2. transformer layers
  for (int l = 0; l < L_; ++l) {
    qkv_kernel<<<BS_, THREED_, 0, stream>>>(
        x, qkv_w + (size_t)l * THREED_ * D_, qkv_b + (size_t)l * THREED_, qkv);
    attn_kernel<<<B_ * H_ * S_, 128, 0, stream>>>(qkv, o);
    proj_residual_ln_kernel<D_><<<BS_, D_, 0, stream>>>(
        x, o, out_w + (size_t)l * D_ * D_, out_b + (size_t)l * D_,
        ln1_g + (size_t)l * D_, ln1_b + (size_t)l * D_);
    ff1_kernel<<<BS_, DFF_, 0, stream>>>(
        x, ff1_w + (size_t)l * DFF_ * D_, ff1_b + (size_t)l * DFF_, ffh);
    proj_residual_ln_kernel<DFF_><<<BS_, D_, 0, stream>>>(
        x, ffh, ff2_w + (size_t)l * D_ * DFF_, ff2_b + (size_t)l * D_,
        ln2_g + (size_t)l * D_, ln2_b + (size_t)l * D_);
  }

  // 3. head
  head_kernel<<<W_ * B_, 256, 0, stream>>>(
      x, noise, proj_w1, proj_b1, proj_w2, proj_b2,
      ex_w1, ex_b1, ex_w2, ex_b2, out);
}

// Round 2
// 3544.045 us; speedup vs baseline: 3.6692x; 3.6692x over previous
//
#include <hip/hip_runtime.h>
#include <math.h>

#define B_ 128
#define S_ 100
#define W_ 20
#define D_ 192
#define L_ 6
#define H_ 8
#define DFF_ 256
#define DH_ 24
#define BS_ (B_*S_)
#define THREED_ 576

__device__ __forceinline__ float posenc(int s, int c) {
  float freq = expf(-logf(10000.f) * (float)(2 * (c >> 1)) / (float)D_);
  float ang = (float)s * freq;
  return (c & 1) ? cosf(ang) : sinf(ang);
}

// ---------------------------------------------------------------------------
// Tiled fp32 GEMM: C(M,N) = A(M,K) @ Wt(N,K)^T + bias, optional ReLU.
// BM=128, BN=64, BK=64. 256 threads, each computes 8x4 (rows ty+16i, cols
// tx+16j -- cyclic so LDS float4 reads are conflict-free at pitch 68).
// Requires M%128==0, N%64==0, K%64==0. All satisfied here.
// ---------------------------------------------------------------------------
template <bool RELU>
__global__ __launch_bounds__(256)
void gemm_kernel(const float* __restrict__ A, const float* __restrict__ Wt,
                 const float* __restrict__ bias, float* __restrict__ C,
                 int M, int N, int K)
{
  const int LDA = 68, LDB = 68;
  __shared__ float As[128 * 68];
  __shared__ float Bs[64 * 68];
  int tid = threadIdx.x;
  int tx = tid & 15, ty = tid >> 4;
  int bm = blockIdx.y * 128, bn = blockIdx.x * 64;
  int c4 = tx * 4, r0 = ty;

  float acc[8][4];
  #pragma unroll
  for (int i = 0; i < 8; ++i)
    #pragma unroll
    for (int j = 0; j < 4; ++j) acc[i][j] = 0.f;

  for (int k0 = 0; k0 < K; k0 += 64) {
    #pragma unroll
    for (int i = 0; i < 8; ++i) {
      float4 v = *(const float4*)(A + (size_t)(bm + r0 + 16 * i) * K + k0 + c4);
      *(float4*)&As[(r0 + 16 * i) * LDA + c4] = v;
    }
    #pragma unroll
    for (int i = 0; i < 4; ++i) {
      float4 v = *(const float4*)(Wt + (size_t)(bn + r0 + 16 * i) * K + k0 + c4);
      *(float4*)&Bs[(r0 + 16 * i) * LDB + c4] = v;
    }
    __syncthreads();
    #pragma unroll
    for (int kk = 0; kk < 64; kk += 4) {
      float4 a[8], b[4];
      #pragma unroll
      for (int i = 0; i < 8; ++i) a[i] = *(const float4*)&As[(ty + 16 * i) * LDA + kk];
      #pragma unroll
      for (int j = 0; j < 4; ++j) b[j] = *(const float4*)&Bs[(tx + 16 * j) * LDB + kk];
      #pragma unroll
      for (int i = 0; i < 8; ++i)
        #pragma unroll
        for (int j = 0; j < 4; ++j)
          acc[i][j] += a[i].x * b[j].x + a[i].y * b[j].y + a[i].z * b[j].z + a[i].w * b[j].w;
    }
    __syncthreads();
  }
  #pragma unroll
  for (int j = 0; j < 4; ++j) {
    int n = bn + tx + 16 * j;
    float bb = bias[n];
    #pragma unroll
    for (int i = 0; i < 8; ++i) {
      float v = acc[i][j] + bb;
      if (RELU) v = fmaxf(v, 0.f);
      C[(size_t)(bm + ty + 16 * i) * N + n] = v;
    }
  }
}

// ---------------------------------------------------------------------------
// Fused encoder: block = 4 bs (80 (bs,w) rows), 256 threads.
// Builds wcomb tiles in LDS (embeds + spatial MLP), register-blocked GEMM vs
// LDS-staged wfuse weights, masked window-avg + posenc epilogue, then the
// mouse/activity/keyboard fusion for x[:,128:192]. 64000 B static LDS.
// ---------------------------------------------------------------------------
__global__ __launch_bounds__(256)
void encode_fused_kernel(
    const int* __restrict__ title_idx, const int* __restrict__ class_idx,
    const int* __restrict__ process_idx, const int* __restrict__ activity_type,
    const float* __restrict__ mouse_pos, const float* __restrict__ rect,
    const float* __restrict__ flags, const float* __restrict__ keyboard_active,
    const float* __restrict__ window_mask,
    const float* __restrict__ title_emb, const float* __restrict__ class_emb,
    const float* __restrict__ process_emb,
    const float* __restrict__ sw1, const float* __restrict__ sb1,
    const float* __restrict__ sw2, const float* __restrict__ sb2,
    const float* __restrict__ wfw, const float* __restrict__ wfb,
    const float* __restrict__ mw1, const float* __restrict__ mb1,
    const float* __restrict__ mw2, const float* __restrict__ mb2,
    const float* __restrict__ act_emb, const float* __restrict__ kbw,
    const float* __restrict__ kbb,
    const float* __restrict__ afw, const float* __restrict__ afb,
    float* __restrict__ x)
{
  __shared__ float wcombS[80 * 132];   // A tile: 80 rows x 128 (pitch 132)
  __shared__ float BsBuf[64 * 68];     // wfw tile; reused as afA/afB in phase 3
  __shared__ float hidS[16 * 68];      // spatial hidden; reused as avgS

  int tid = threadIdx.x;
  int tx = tid & 15, ty = tid >> 4;
  int bs0 = blockIdx.x * 4;
  int row0 = bs0 * W_;                 // 80 consecutive (bs,w) rows

  // phase 1a: embedding gathers -> wcombS[:, 0:96]
  for (int idx = tid; idx < 80 * 96; idx += 256) {
    int r = idx / 96, c = idx - r * 96;
    int rg = row0 + r;
    float v;
    if (c < 32)      v = title_emb[title_idx[rg] * 32 + c];
    else if (c < 64) v = class_emb[class_idx[rg] * 32 + (c - 32)];
    else             v = process_emb[process_idx[rg] * 32 + (c - 64)];
    wcombS[r * 132 + c] = v;
  }

  // phase 1b: spatial MLP -> wcombS[:, 96:128], 16 rows per chunk
  for (int chunk = 0; chunk < 5; ++chunk) {
    int r = chunk * 16 + ty;
    int rg = row0 + r;
    float4 rc = *(const float4*)(rect + (size_t)rg * 4);
    float f0 = flags[rg * 2], f1 = flags[rg * 2 + 1];
    __syncthreads();   // previous chunk's hidS reads complete
    #pragma unroll
    for (int u = 0; u < 4; ++u) {
      int cc = tx + 16 * u;
      const float* w1 = sw1 + cc * 6;
      float a = sb1[cc] + w1[0]*rc.x + w1[1]*rc.y + w1[2]*rc.z + w1[3]*rc.w
                        + w1[4]*f0 + w1[5]*f1;
      hidS[ty * 68 + cc] = fmaxf(a, 0.f);
    }
    __syncthreads();
    #pragma unroll
    for (int v2 = 0; v2 < 2; ++v2) {
      int cc = tx + 16 * v2;
      const float4* w2 = (const float4*)(sw2 + cc * 64);
      const float4* hp = (const float4*)&hidS[ty * 68];
      float a = sb2[cc];
      #pragma unroll
      for (int k4 = 0; k4 < 16; ++k4) {
        float4 w = w2[k4], h = hp[k4];
        a += w.x*h.x + w.y*h.y + w.z*h.z + w.w*h.w;
      }
      wcombS[r * 132 + 96 + cc] = a;
    }
  }
  __syncthreads();

  // phase 2: wfuse GEMM (80 rows x 128 ch x K=128) + masked avg epilogue.
  // thread owns rows 5*ty..5*ty+4 (within one bs since 5|20), cols tx+16j.
  for (int nt = 0; nt < 2; ++nt) {
    float acc[5][4];
    #pragma unroll
    for (int i = 0; i < 5; ++i)
      #pragma unroll
      for (int j = 0; j < 4; ++j) acc[i][j] = 0.f;

    for (int kt = 0; kt < 2; ++kt) {
      #pragma unroll
      for (int i = 0; i < 4; ++i) {
        float4 v = *(const float4*)(wfw + (size_t)(nt * 64 + ty + 16 * i) * 128 + kt * 64 + tx * 4);
        *(float4*)&BsBuf[(ty + 16 * i) * 68 + tx * 4] = v;
      }
      __syncthreads();
      #pragma unroll
      for (int kk = 0; kk < 64; kk += 4) {
        float4 a[5], b[4];
        #pragma unroll
        for (int i = 0; i < 5; ++i)
          a[i] = *(const float4*)&wcombS[(5 * ty + i) * 132 + kt * 64 + kk];
        #pragma unroll
        for (int j = 0; j < 4; ++j)
          b[j] = *(const float4*)&BsBuf[(tx + 16 * j) * 68 + kk];
        #pragma unroll
        for (int i = 0; i < 5; ++i)
          #pragma unroll
          for (int j = 0; j < 4; ++j)
            acc[i][j] += a[i].x*b[j].x + a[i].y*b[j].y + a[i].z*b[j].z + a[i].w*b[j].w;
      }
      __syncthreads();
    }
    // epilogue: relu(+bias) * mask, partial sum over this thread's 5 rows
    float part[4] = {0.f, 0.f, 0.f, 0.f};
    #pragma unroll
    for (int i = 0; i < 5; ++i) {
      int rg = row0 + 5 * ty + i;
      float mk = window_mask[rg];
      #pragma unroll
      for (int j = 0; j < 4; ++j) {
        float v = fmaxf(acc[i][j] + wfb[nt * 64 + tx + 16 * j], 0.f);
        part[j] += v * mk;
      }
    }
    #pragma unroll
    for (int j = 0; j < 4; ++j) hidS[ty * 68 + tx + 16 * j] = part[j];  // avgS
    __syncthreads();
    {
      int u = ty >> 2, bl = ty & 3;
      int cl = tx + 16 * u;            // 0..63
      float s = hidS[(bl * 4 + 0) * 68 + cl] + hidS[(bl * 4 + 1) * 68 + cl]
              + hidS[(bl * 4 + 2) * 68 + cl] + hidS[(bl * 4 + 3) * 68 + cl];
      float avg = s * (1.f / (float)W_);
      int bsg = bs0 + bl;
      int cg = nt * 64 + cl;
      x[(size_t)bsg * D_ + cg] = avg + posenc(bsg % S_, cg);
    }
    __syncthreads();
  }

  // phase 3: activity fusion -> x[:, 128:192]
  float* afA = BsBuf;                  // [4][68]
  float* afB = BsBuf + 4 * 68;         // [4][68]
  int bl = tid >> 6, ln = tid & 63;
  int bsg = bs0 + bl;
  __syncthreads();
  if (ln < 32) {
    float mx = mouse_pos[bsg * 2 + 0] * (1.f / 1920.f);
    float my = mouse_pos[bsg * 2 + 1] * (1.f / 1080.f);
    afA[bl * 68 + ln] = fmaxf(mw1[ln * 2] * mx + mw1[ln * 2 + 1] * my + mb1[ln], 0.f);
  }
  __syncthreads();
  float cv;
  if (ln < 32) {
    float a = mb2[ln];
    #pragma unroll 8
    for (int k = 0; k < 32; ++k) a += mw2[ln * 32 + k] * afA[bl * 68 + k];
    cv = a;
  } else if (ln < 48) {
    cv = act_emb[activity_type[bsg] * 16 + (ln - 32)];
  } else {
    cv = kbw[ln - 48] * keyboard_active[bsg] + kbb[ln - 48];
  }
  __syncthreads();
  afB[bl * 68 + ln] = cv;
  __syncthreads();
  {
    float a = afb[ln];
    const float4* w4 = (const float4*)(afw + ln * 64);
    const float4* cp = (const float4*)&afB[bl * 68];
    #pragma unroll
    for (int k4 = 0; k4 < 16; ++k4) {
      float4 w = w4[k4], c = cp[k4];
      a += w.x*c.x + w.y*c.y + w.z*c.z + w.w*c.w;
    }
    float v = fmaxf(a, 0.f);
    int cg = 128 + ln;
    x[(size_t)bsg * D_ + cg] = v + posenc(bsg % S_, cg);
  }
}

// ---------------------------------------------------------------------------
// Attention: one block per (b,h), 256 threads (4 waves, wave per query slice).
// K staged transposed [d][k] (pitch 132) so score loads are lane-contiguous.
// ---------------------------------------------------------------------------
__global__ __launch_bounds__(256)
void attn_kernel(const float* __restrict__ qkv, float* __restrict__ o)
{
  int bh = blockIdx.x;
  int hh = bh & 7, b = bh >> 3;
  int tid = threadIdx.x, wv = tid >> 6, ln = tid & 63;
  __shared__ float Qs[100 * 25];
  __shared__ float Ks[24 * 132];
  __shared__ float Vs[100 * 25];
  __shared__ float Ps[4 * 132];
  const float* base = qkv + (size_t)b * S_ * THREED_ + hh * DH_;
  for (int i = tid; i < 2400; i += 256) {
    int r = i / 24, d = i - r * 24;
    const float* rp = base + (size_t)r * THREED_;
    Qs[r * 25 + d]  = rp[d];
    Ks[d * 132 + r] = rp[D_ + d];
    Vs[r * 25 + d]  = rp[2 * D_ + d];
  }
  __syncthreads();
  const float scale = 0.20412414523193154f;  // 1/sqrt(24)
  int k1 = ln + 64;
  bool k1v = (k1 < S_);
  for (int q = wv; q < S_; q += 4) {
    float s0 = 0.f, s1 = 0.f;
    #pragma unroll
    for (int d = 0; d < DH_; ++d) {
      float qd = Qs[q * 25 + d];
      s0 += qd * Ks[d * 132 + ln];
      s1 += qd * Ks[d * 132 + k1];
    }
    s0 *= scale;
    s1 = k1v ? s1 * scale : -1e30f;
    float mx = fmaxf(s0, s1);
    #pragma unroll
    for (int off = 32; off; off >>= 1) mx = fmaxf(mx, __shfl_xor(mx, off));
    float e0 = expf(s0 - mx);
    float e1 = k1v ? expf(s1 - mx) : 0.f;
    float sm = e0 + e1;
    #pragma unroll
    for (int off = 32; off; off >>= 1) sm += __shfl_xor(sm, off);
    float inv = 1.f / sm;
    Ps[wv * 132 + ln] = e0;
    if (k1v) Ps[wv * 132 + k1] = e1;
    float acc = 0.f;
    int d = ln % 24, g = ln / 24;
    if (ln < 48) {
      int kb = g * 50;
      for (int k = kb; k < kb + 50; ++k)
        acc += Ps[wv * 132 + k] * Vs[k * 25 + d];
    }
    float other = __shfl(acc, (ln + 24) & 63);
    if (ln < 24)
      o[((size_t)(b * S_ + q)) * D_ + hh * DH_ + ln] = (acc + other) * inv;
  }
}

// ---------------------------------------------------------------------------
// Residual + LayerNorm, wave per row, 4 rows per block. h = LN(h+inp)*g+b.
// ---------------------------------------------------------------------------
__global__ __launch_bounds__(256)
void residual_ln_kernel(float* __restrict__ h, const float* __restrict__ inp,
                        const float* __restrict__ g, const float* __restrict__ bb)
{
  int row = blockIdx.x * 4 + (threadIdx.x >> 6);
  int ln = threadIdx.x & 63;
  float* hr = h + (size_t)row * D_;
  const float* ir = inp + (size_t)row * D_;
  float v0 = hr[ln]        + ir[ln];
  float v1 = hr[ln + 64]   + ir[ln + 64];
  float v2 = hr[ln + 128]  + ir[ln + 128];
  float s = v0 + v1 + v2;
  #pragma unroll
  for (int off = 32; off; off >>= 1) s += __shfl_xor(s, off);
  float mean = s * (1.f / (float)D_);
  float d0 = v0 - mean, d1 = v1 - mean, d2 = v2 - mean;
  float vs = d0 * d0 + d1 * d1 + d2 * d2;
  #pragma unroll
  for (int off = 32; off; off >>= 1) vs += __shfl_xor(vs, off);
  float inv = rsqrtf(vs * (1.f / (float)D_) + 1e-5f);
  hr[ln]       = d0 * inv * g[ln]       + bb[ln];
  hr[ln + 64]  = d1 * inv * g[ln + 64]  + bb[ln + 64];
  hr[ln + 128] = d2 * inv * g[ln + 128] + bb[ln + 128];
}

// ---------------------------------------------------------------------------
// Head: one block per (w,b) slot, 256 threads, float4 weight loads.
// ---------------------------------------------------------------------------
__global__ __launch_bounds__(256)
void head_kernel(const float* __restrict__ x, const float* __restrict__ noise,
                 const float* __restrict__ pw1, const float* __restrict__ pb1,
                 const float* __restrict__ pw2, const float* __restrict__ pb2,
                 const float* __restrict__ ew1, const float* __restrict__ eb1,
                 const float* __restrict__ ew2, const float* __restrict__ eb2,
                 float* __restrict__ out)
{
  int idx = blockIdx.x;     // w*B + b
  int b = idx & 127, w = idx >> 7;
  int tid = threadIdx.x;
  __shared__ float slot[192];
  __shared__ float ph[256];
  __shared__ float eh[128];
  if (tid < 192)
    slot[tid] = x[((size_t)b * S_ + (S_ - 1)) * D_ + tid]
              + noise[((size_t)w * B_ + b) * D_ + tid] * 0.1f;
  __syncthreads();
  {
    const float4* wr = (const float4*)(pw1 + (size_t)tid * D_);
    const float4* sp = (const float4*)slot;
    float a = pb1[tid];
    #pragma unroll 12
    for (int k = 0; k < 48; ++k) {
      float4 wv = wr[k], sv = sp[k];
      a += wv.x*sv.x + wv.y*sv.y + wv.z*sv.z + wv.w*sv.w;
    }
    ph[tid] = fmaxf(a, 0.f);
  }
  if (tid < 128) {
    const float4* wr = (const float4*)(ew1 + (size_t)tid * D_);
    const float4* sp = (const float4*)slot;
    float a = eb1[tid];
    #pragma unroll 12
    for (int k = 0; k < 48; ++k) {
      float4 wv = wr[k], sv = sp[k];
      a += wv.x*sv.x + wv.y*sv.y + wv.z*sv.z + wv.w*sv.w;
    }
    eh[tid] = fmaxf(a, 0.f);
  }
  __syncthreads();
  if (tid < 4) {
    float a = pb2[tid];
    const float4* wr = (const float4*)(pw2 + tid * 256);
    const float4* pp = (const float4*)ph;
    for (int k = 0; k < 64; ++k) {
      float4 wv = wr[k], pv = pp[k];
      a += wv.x*pv.x + wv.y*pv.y + wv.z*pv.z + wv.w*pv.w;
    }
    out[((size_t)b * W_ + w) * 4 + tid] = a;
  }
  if (tid == 4) {
    float a = eb2[0];
    const float4* wr = (const float4*)ew2;
    const float4* pp = (const float4*)eh;
    for (int k = 0; k < 32; ++k) {
      float4 wv = wr[k], pv = pp[k];
      a += wv.x*pv.x + wv.y*pv.y + wv.z*pv.z + wv.w*pv.w;
    }
    out[(size_t)B_ * W_ * 4 + (size_t)b * W_ + w] = 1.f / (1.f + expf(-a));
  }
}

// ---------------------------------------------------------------------------
extern "C" void kernel_launch(void* const* d_in, const int* in_sizes, int n_in,
                              void* d_out, int out_size, void* d_ws, size_t ws_size,
                              hipStream_t stream)
{
  const int*   title_idx       = (const int*)  d_in[0];
  const int*   class_idx       = (const int*)  d_in[1];
  const int*   process_idx     = (const int*)  d_in[2];
  const int*   activity_type   = (const int*)  d_in[3];
  const float* mouse_pos       = (const float*)d_in[4];
  const float* rect            = (const float*)d_in[5];
  const float* flags           = (const float*)d_in[6];
  const float* keyboard_active = (const float*)d_in[7];
  const float* window_mask     = (const float*)d_in[8];
  const float* noise           = (const float*)d_in[9];
  const float* title_emb       = (const float*)d_in[10];
  const float* class_emb       = (const float*)d_in[11];
  const float* process_emb     = (const float*)d_in[12];
  const float* spatial_w1      = (const float*)d_in[13];
  const float* spatial_b1      = (const float*)d_in[14];
  const float* spatial_w2      = (const float*)d_in[15];
  const float* spatial_b2      = (const float*)d_in[16];
  const float* wfuse_w         = (const float*)d_in[17];
  const float* wfuse_b         = (const float*)d_in[18];
  const float* mouse_w1        = (const float*)d_in[19];
  const float* mouse_b1        = (const float*)d_in[20];
  const float* mouse_w2        = (const float*)d_in[21];
  const float* mouse_b2        = (const float*)d_in[22];
  const float* act_emb         = (const float*)d_in[23];
  const float* kbd_w           = (const float*)d_in[24];
  const float* kbd_b           = (const float*)d_in[25];
  const float* afuse_w         = (const float*)d_in[26];
  const float* afuse_b         = (const float*)d_in[27];
  const float* qkv_w           = (const float*)d_in[28];
  const float* qkv_b           = (const float*)d_in[29];
  const float* out_w           = (const float*)d_in[30];
  const float* out_b           = (const float*)d_in[31];
  const float* ff1_w           = (const float*)d_in[32];
  const float* ff1_b           = (const float*)d_in[33];
  const float* ff2_w           = (const float*)d_in[34];
  const float* ff2_b           = (const float*)d_in[35];
  const float* ln1_g           = (const float*)d_in[36];
  const float* ln1_b           = (const float*)d_in[37];
  const float* ln2_g           = (const float*)d_in[38];
  const float* ln2_b           = (const float*)d_in[39];
  const float* proj_w1         = (const float*)d_in[40];
  const float* proj_b1         = (const float*)d_in[41];
  const float* proj_w2         = (const float*)d_in[42];
  const float* proj_b2         = (const float*)d_in[43];
  const float* ex_w1           = (const float*)d_in[44];
  const float* ex_b1           = (const float*)d_in[45];
  const float* ex_w2           = (const float*)d_in[46];
  const float* ex_b2           = (const float*)d_in[47];

  float* out = (float*)d_out;

  float* ws   = (float*)d_ws;
  float* x    = ws;                                  // BS*192
  float* qkvb = x    + (size_t)BS_ * D_;             // BS*576
  float* attno= qkvb + (size_t)BS_ * THREED_;        // BS*192
  float* tmp  = attno+ (size_t)BS_ * D_;             // BS*256
  (void)ws_size; (void)n_in; (void)in_sizes; (void)out_size;

  // 1. fused encoder
  encode_fused_kernel<<<BS_ / 4, 256, 0, stream>>>(
      title_idx, class_idx, process_idx, activity_type, mouse_pos, rect, flags,
      keyboard_active, window_mask, title_emb, class_emb, process_emb,
      spatial_w1, spatial_b1, spatial_w2, spatial_b2, wfuse_w, wfuse_b,
      mouse_w1, mouse_b1, mouse_w2, mouse_b2, act_emb, kbd_w, kbd_b,
      afuse_w, afuse_b, x);

  // 2. transformer layers
  for (int l = 0; l < L_; ++l) {
    gemm_kernel<false><<<dim3(THREED_ / 64, BS_ / 128), 256, 0, stream>>>(
        x, qkv_w + (size_t)l * THREED_ * D_, qkv_b + (size_t)l * THREED_,
        qkvb, BS_, THREED_, D_);
    attn_kernel<<<B_ * H_, 256, 0, stream>>>(qkvb, attno);
    gemm_kernel<false><<<dim3(D_ / 64, BS_ / 128), 256, 0, stream>>>(
        attno, out_w + (size_t)l * D_ * D_, out_b + (size_t)l * D_,
        tmp, BS_, D_, D_);
    residual_ln_kernel<<<BS_ / 4, 256, 0, stream>>>(
        x, tmp, ln1_g + (size_t)l * D_, ln1_b + (size_t)l * D_);
    gemm_kernel<true><<<dim3(DFF_ / 64, BS_ / 128), 256, 0, stream>>>(
        x, ff1_w + (size_t)l * DFF_ * D_, ff1_b + (size_t)l * DFF_,
        tmp, BS_, DFF_, D_);
    gemm_kernel<false><<<dim3(D_ / 64, BS_ / 128), 256, 0, stream>>>(
        tmp, ff2_w + (size_t)l * D_ * DFF_, ff2_b + (size_t)l * D_,
        attno, BS_, D_, DFF_);
    residual_ln_kernel<<<BS_ / 4, 256, 0, stream>>>(
        x, attno, ln2_g + (size_t)l * D_, ln2_b + (size_t)l * D_);
  }

  // 3. head
  head_kernel<<<W_ * B_, 256, 0, stream>>>(
      x, noise, proj_w1, proj_b1, proj_w2, proj_b2,
      ex_w1, ex_b1, ex_w2, ex_b2, out);
}

// Round 4
// 1604.068 us; speedup vs baseline: 8.1067x; 2.2094x over previous
//
#include <hip/hip_runtime.h>
#include <hip/hip_bf16.h>
#include <math.h>

#define B_ 128
#define S_ 100
#define W_ 20
#define D_ 192
#define L_ 6
#define H_ 8
#define DFF_ 256
#define DH_ 24
#define BS_ (B_*S_)
#define THREED_ 576

typedef short short8 __attribute__((ext_vector_type(8)));
typedef float floatx16 __attribute__((ext_vector_type(16)));

__device__ __forceinline__ float posenc(int s, int c) {
  float freq = expf(-logf(10000.f) * (float)(2 * (c >> 1)) / (float)D_);
  float ang = (float)s * freq;
  return (c & 1) ? cosf(ang) : sinf(ang);
}

// ---------------------------------------------------------------------------
// fp32 -> bf16 conversion (weights). n must be divisible by 8.
// ---------------------------------------------------------------------------
__global__ __launch_bounds__(256)
void convert_kernel(const float* __restrict__ src, __hip_bfloat16* __restrict__ dst)
{
  int i = (blockIdx.x * 256 + threadIdx.x) * 8;
  float4 v0 = *(const float4*)(src + i);
  float4 v1 = *(const float4*)(src + i + 4);
  __hip_bfloat162* d2 = (__hip_bfloat162*)(dst + i);
  d2[0] = __float22bfloat162_rn(make_float2(v0.x, v0.y));
  d2[1] = __float22bfloat162_rn(make_float2(v0.z, v0.w));
  d2[2] = __float22bfloat162_rn(make_float2(v1.x, v1.y));
  d2[3] = __float22bfloat162_rn(make_float2(v1.z, v1.w));
}

// ---------------------------------------------------------------------------
// bf16 MFMA GEMM: C(M,N) = A(M,K) @ W(N,K)^T + bias.
// 128 threads = 2 waves. BM=128 (wave owns 64 rows), BN=64, BK=32.
// Wave computes 64x64 via 2x2 mfma_f32_32x32x16_bf16 tiles (acc 4x16 fp32).
// Requires: M%128==0, N%64==0, K%32==0.
// C/D layout: col=lane&31, row=(reg&3)+8*(reg>>2)+4*(lane>>5)  [m74/m101]
// A frag: A[m=lane&31][k=(lane>>5)*8+j]; B frag symmetric (NT layout).
// NOTE: float4 = 8 bf16. A row (32 bf16) = 4 float4s; B row = 2 threads x 2.
// ---------------------------------------------------------------------------
template <bool RELU, bool OUTF, bool OUTB>
__global__ __launch_bounds__(128)
void mfma_gemm_kernel(const __hip_bfloat16* __restrict__ A,
                      const __hip_bfloat16* __restrict__ W,
                      const float* __restrict__ bias,
                      float* __restrict__ Cf, __hip_bfloat16* __restrict__ Cb,
                      int N, int K)
{
  __shared__ __align__(16) __hip_bfloat16 Asl[128 * 40];
  __shared__ __align__(16) __hip_bfloat16 Bsl[64 * 40];
  int tid = threadIdx.x, lane = tid & 63, wv = tid >> 6;
  int bm = blockIdx.y * 128, bn = blockIdx.x * 64;
  int m32 = lane & 31, half = lane >> 5;

  floatx16 acc[2][2];
  #pragma unroll
  for (int mt = 0; mt < 2; ++mt)
    #pragma unroll
    for (int nt = 0; nt < 2; ++nt)
      #pragma unroll
      for (int r = 0; r < 16; ++r) acc[mt][nt][r] = 0.f;

  for (int k0 = 0; k0 < K; k0 += 32) {
    {  // stage A: thread t -> row bm+t, 32 bf16 = 64 B = 4 float4
      const float4* src = (const float4*)(A + (size_t)(bm + tid) * K + k0);
      float4* dst = (float4*)&Asl[tid * 40];
      dst[0] = src[0]; dst[1] = src[1]; dst[2] = src[2]; dst[3] = src[3];
    }
    {  // stage B: thread t -> row bn+(t>>1), half (t&1): 16 bf16 = 2 float4
      int r = tid >> 1, h = tid & 1;
      const float4* src = (const float4*)(W + (size_t)(bn + r) * K + k0 + h * 16);
      float4* dst = (float4*)&Bsl[r * 40 + h * 16];
      dst[0] = src[0]; dst[1] = src[1];
    }
    __syncthreads();
    #pragma unroll
    for (int kc = 0; kc < 2; ++kc) {
      int ko = kc * 16 + half * 8;
      short8 a0 = *(const short8*)&Asl[(wv * 64 + m32) * 40 + ko];
      short8 a1 = *(const short8*)&Asl[(wv * 64 + 32 + m32) * 40 + ko];
      short8 b0 = *(const short8*)&Bsl[m32 * 40 + ko];
      short8 b1 = *(const short8*)&Bsl[(32 + m32) * 40 + ko];
      acc[0][0] = __builtin_amdgcn_mfma_f32_32x32x16_bf16(a0, b0, acc[0][0], 0, 0, 0);
      acc[0][1] = __builtin_amdgcn_mfma_f32_32x32x16_bf16(a0, b1, acc[0][1], 0, 0, 0);
      acc[1][0] = __builtin_amdgcn_mfma_f32_32x32x16_bf16(a1, b0, acc[1][0], 0, 0, 0);
      acc[1][1] = __builtin_amdgcn_mfma_f32_32x32x16_bf16(a1, b1, acc[1][1], 0, 0, 0);
    }
    __syncthreads();
  }

  float bb[2] = { bias[bn + m32], bias[bn + 32 + m32] };
  #pragma unroll
  for (int mt = 0; mt < 2; ++mt) {
    int rowbase = bm + wv * 64 + mt * 32 + 4 * half;
    #pragma unroll
    for (int nt = 0; nt < 2; ++nt) {
      int col = bn + nt * 32 + m32;
      #pragma unroll
      for (int r = 0; r < 16; ++r) {
        int row = rowbase + (r & 3) + 8 * (r >> 2);
        float v = acc[mt][nt][r] + bb[nt];
        if (RELU) v = fmaxf(v, 0.f);
        if (OUTF) Cf[(size_t)row * N + col] = v;
        if (OUTB) Cb[(size_t)row * N + col] = __float2bfloat16(v);
      }
    }
  }
}

// ---------------------------------------------------------------------------
// Fused encoder (fp32): also emits bf16 mirror of x.
// ---------------------------------------------------------------------------
__global__ __launch_bounds__(256)
void encode_fused_kernel(
    const int* __restrict__ title_idx, const int* __restrict__ class_idx,
    const int* __restrict__ process_idx, const int* __restrict__ activity_type,
    const float* __restrict__ mouse_pos, const float* __restrict__ rect,
    const float* __restrict__ flags, const float* __restrict__ keyboard_active,
    const float* __restrict__ window_mask,
    const float* __restrict__ title_emb, const float* __restrict__ class_emb,
    const float* __restrict__ process_emb,
    const float* __restrict__ sw1, const float* __restrict__ sb1,
    const float* __restrict__ sw2, const float* __restrict__ sb2,
    const float* __restrict__ wfw, const float* __restrict__ wfb,
    const float* __restrict__ mw1, const float* __restrict__ mb1,
    const float* __restrict__ mw2, const float* __restrict__ mb2,
    const float* __restrict__ act_emb, const float* __restrict__ kbw,
    const float* __restrict__ kbb,
    const float* __restrict__ afw, const float* __restrict__ afb,
    float* __restrict__ x, __hip_bfloat16* __restrict__ xb)
{
  __shared__ float wcombS[80 * 132];
  __shared__ float BsBuf[64 * 68];
  __shared__ float hidS[16 * 68];

  int tid = threadIdx.x;
  int tx = tid & 15, ty = tid >> 4;
  int bs0 = blockIdx.x * 4;
  int row0 = bs0 * W_;

  for (int idx = tid; idx < 80 * 96; idx += 256) {
    int r = idx / 96, c = idx - r * 96;
    int rg = row0 + r;
    float v;
    if (c < 32)      v = title_emb[title_idx[rg] * 32 + c];
    else if (c < 64) v = class_emb[class_idx[rg] * 32 + (c - 32)];
    else             v = process_emb[process_idx[rg] * 32 + (c - 64)];
    wcombS[r * 132 + c] = v;
  }

  for (int chunk = 0; chunk < 5; ++chunk) {
    int r = chunk * 16 + ty;
    int rg = row0 + r;
    float4 rc = *(const float4*)(rect + (size_t)rg * 4);
    float f0 = flags[rg * 2], f1 = flags[rg * 2 + 1];
    __syncthreads();
    #pragma unroll
    for (int u = 0; u < 4; ++u) {
      int cc = tx + 16 * u;
      const float* w1 = sw1 + cc * 6;
      float a = sb1[cc] + w1[0]*rc.x + w1[1]*rc.y + w1[2]*rc.z + w1[3]*rc.w
                        + w1[4]*f0 + w1[5]*f1;
      hidS[ty * 68 + cc] = fmaxf(a, 0.f);
    }
    __syncthreads();
    #pragma unroll
    for (int v2 = 0; v2 < 2; ++v2) {
      int cc = tx + 16 * v2;
      const float4* w2 = (const float4*)(sw2 + cc * 64);
      const float4* hp = (const float4*)&hidS[ty * 68];
      float a = sb2[cc];
      #pragma unroll
      for (int k4 = 0; k4 < 16; ++k4) {
        float4 w = w2[k4], h = hp[k4];
        a += w.x*h.x + w.y*h.y + w.z*h.z + w.w*h.w;
      }
      wcombS[r * 132 + 96 + cc] = a;
    }
  }
  __syncthreads();

  for (int nt = 0; nt < 2; ++nt) {
    float acc[5][4];
    #pragma unroll
    for (int i = 0; i < 5; ++i)
      #pragma unroll
      for (int j = 0; j < 4; ++j) acc[i][j] = 0.f;

    for (int kt = 0; kt < 2; ++kt) {
      #pragma unroll
      for (int i = 0; i < 4; ++i) {
        float4 v = *(const float4*)(wfw + (size_t)(nt * 64 + ty + 16 * i) * 128 + kt * 64 + tx * 4);
        *(float4*)&BsBuf[(ty + 16 * i) * 68 + tx * 4] = v;
      }
      __syncthreads();
      #pragma unroll
      for (int kk = 0; kk < 64; kk += 4) {
        float4 a[5], b[4];
        #pragma unroll
        for (int i = 0; i < 5; ++i)
          a[i] = *(const float4*)&wcombS[(5 * ty + i) * 132 + kt * 64 + kk];
        #pragma unroll
        for (int j = 0; j < 4; ++j)
          b[j] = *(const float4*)&BsBuf[(tx + 16 * j) * 68 + kk];
        #pragma unroll
        for (int i = 0; i < 5; ++i)
          #pragma unroll
          for (int j = 0; j < 4; ++j)
            acc[i][j] += a[i].x*b[j].x + a[i].y*b[j].y + a[i].z*b[j].z + a[i].w*b[j].w;
      }
      __syncthreads();
    }
    float part[4] = {0.f, 0.f, 0.f, 0.f};
    #pragma unroll
    for (int i = 0; i < 5; ++i) {
      int rg = row0 + 5 * ty + i;
      float mk = window_mask[rg];
      #pragma unroll
      for (int j = 0; j < 4; ++j) {
        float v = fmaxf(acc[i][j] + wfb[nt * 64 + tx + 16 * j], 0.f);
        part[j] += v * mk;
      }
    }
    #pragma unroll
    for (int j = 0; j < 4; ++j) hidS[ty * 68 + tx + 16 * j] = part[j];
    __syncthreads();
    {
      int u = ty >> 2, bl = ty & 3;
      int cl = tx + 16 * u;
      float s = hidS[(bl * 4 + 0) * 68 + cl] + hidS[(bl * 4 + 1) * 68 + cl]
              + hidS[(bl * 4 + 2) * 68 + cl] + hidS[(bl * 4 + 3) * 68 + cl];
      float avg = s * (1.f / (float)W_);
      int bsg = bs0 + bl;
      int cg = nt * 64 + cl;
      float v = avg + posenc(bsg % S_, cg);
      x[(size_t)bsg * D_ + cg] = v;
      xb[(size_t)bsg * D_ + cg] = __float2bfloat16(v);
    }
    __syncthreads();
  }

  float* afA = BsBuf;
  float* afB = BsBuf + 4 * 68;
  int bl = tid >> 6, ln = tid & 63;
  int bsg = bs0 + bl;
  __syncthreads();
  if (ln < 32) {
    float mx = mouse_pos[bsg * 2 + 0] * (1.f / 1920.f);
    float my = mouse_pos[bsg * 2 + 1] * (1.f / 1080.f);
    afA[bl * 68 + ln] = fmaxf(mw1[ln * 2] * mx + mw1[ln * 2 + 1] * my + mb1[ln], 0.f);
  }
  __syncthreads();
  float cv;
  if (ln < 32) {
    float a = mb2[ln];
    #pragma unroll 8
    for (int k = 0; k < 32; ++k) a += mw2[ln * 32 + k] * afA[bl * 68 + k];
    cv = a;
  } else if (ln < 48) {
    cv = act_emb[activity_type[bsg] * 16 + (ln - 32)];
  } else {
    cv = kbw[ln - 48] * keyboard_active[bsg] + kbb[ln - 48];
  }
  __syncthreads();
  afB[bl * 68 + ln] = cv;
  __syncthreads();
  {
    float a = afb[ln];
    const float4* w4 = (const float4*)(afw + ln * 64);
    const float4* cp = (const float4*)&afB[bl * 68];
    #pragma unroll
    for (int k4 = 0; k4 < 16; ++k4) {
      float4 w = w4[k4], c = cp[k4];
      a += w.x*c.x + w.y*c.y + w.z*c.z + w.w*c.w;
    }
    float v = fmaxf(a, 0.f);
    int cg = 128 + ln;
    float o = v + posenc(bsg % S_, cg);
    x[(size_t)bsg * D_ + cg] = o;
    xb[(size_t)bsg * D_ + cg] = __float2bfloat16(o);
  }
}

// ---------------------------------------------------------------------------
// Attention: bf16 in (qkv), bf16 out (o). fp32 math in LDS/registers.
// One block per (b,h), 256 threads, wave-per-query.
// ---------------------------------------------------------------------------
__global__ __launch_bounds__(256)
void attn_kernel(const __hip_bfloat16* __restrict__ qkv, __hip_bfloat16* __restrict__ o)
{
  int bh = blockIdx.x;
  int hh = bh & 7, b = bh >> 3;
  int tid = threadIdx.x, wv = tid >> 6, ln = tid & 63;
  __shared__ float Qs[100 * 25];
  __shared__ float Ks[24 * 132];
  __shared__ float Vs[100 * 25];
  __shared__ float Ps[4 * 132];
  const __hip_bfloat16* base = qkv + (size_t)b * S_ * THREED_ + hh * DH_;
  for (int i = tid; i < 2400; i += 256) {
    int r = i / 24, d = i - r * 24;
    const __hip_bfloat16* rp = base + (size_t)r * THREED_;
    Qs[r * 25 + d]  = __bfloat162float(rp[d]);
    Ks[d * 132 + r] = __bfloat162float(rp[D_ + d]);
    Vs[r * 25 + d]  = __bfloat162float(rp[2 * D_ + d]);
  }
  __syncthreads();
  const float scale = 0.20412414523193154f;  // 1/sqrt(24)
  int k1 = ln + 64;
  bool k1v = (k1 < S_);
  for (int q = wv; q < S_; q += 4) {
    float s0 = 0.f, s1 = 0.f;
    #pragma unroll
    for (int d = 0; d < DH_; ++d) {
      float qd = Qs[q * 25 + d];
      s0 += qd * Ks[d * 132 + ln];
      s1 += qd * Ks[d * 132 + k1];
    }
    s0 *= scale;
    s1 = k1v ? s1 * scale : -1e30f;
    float mx = fmaxf(s0, s1);
    #pragma unroll
    for (int off = 32; off; off >>= 1) mx = fmaxf(mx, __shfl_xor(mx, off));
    float e0 = expf(s0 - mx);
    float e1 = k1v ? expf(s1 - mx) : 0.f;
    float sm = e0 + e1;
    #pragma unroll
    for (int off = 32; off; off >>= 1) sm += __shfl_xor(sm, off);
    float inv = 1.f / sm;
    Ps[wv * 132 + ln] = e0;
    if (k1v) Ps[wv * 132 + k1] = e1;
    float acc = 0.f;
    int d = ln % 24, g = ln / 24;
    if (ln < 48) {
      int kb = g * 50;
      for (int k = kb; k < kb + 50; ++k)
        acc += Ps[wv * 132 + k] * Vs[k * 25 + d];
    }
    float other = __shfl(acc, (ln + 24) & 63);
    if (ln < 24)
      o[((size_t)(b * S_ + q)) * D_ + hh * DH_ + ln] = __float2bfloat16((acc + other) * inv);
  }
}

// ---------------------------------------------------------------------------
// Residual + LayerNorm, wave per row. Writes fp32 x and bf16 mirror xb.
// ---------------------------------------------------------------------------
__global__ __launch_bounds__(256)
void residual_ln_kernel(float* __restrict__ h, const float* __restrict__ inp,
                        const float* __restrict__ g, const float* __restrict__ bb,
                        __hip_bfloat16* __restrict__ hb)
{
  int row = blockIdx.x * 4 + (threadIdx.x >> 6);
  int ln = threadIdx.x & 63;
  float* hr = h + (size_t)row * D_;
  __hip_bfloat16* hbr = hb + (size_t)row * D_;
  const float* ir = inp + (size_t)row * D_;
  float v0 = hr[ln]        + ir[ln];
  float v1 = hr[ln + 64]   + ir[ln + 64];
  float v2 = hr[ln + 128]  + ir[ln + 128];
  float s = v0 + v1 + v2;
  #pragma unroll
  for (int off = 32; off; off >>= 1) s += __shfl_xor(s, off);
  float mean = s * (1.f / (float)D_);
  float d0 = v0 - mean, d1 = v1 - mean, d2 = v2 - mean;
  float vs = d0 * d0 + d1 * d1 + d2 * d2;
  #pragma unroll
  for (int off = 32; off; off >>= 1) vs += __shfl_xor(vs, off);
  float inv = rsqrtf(vs * (1.f / (float)D_) + 1e-5f);
  float o0 = d0 * inv * g[ln]       + bb[ln];
  float o1 = d1 * inv * g[ln + 64]  + bb[ln + 64];
  float o2 = d2 * inv * g[ln + 128] + bb[ln + 128];
  hr[ln] = o0; hr[ln + 64] = o1; hr[ln + 128] = o2;
  hbr[ln] = __float2bfloat16(o0);
  hbr[ln + 64] = __float2bfloat16(o1);
  hbr[ln + 128] = __float2bfloat16(o2);
}

// ---------------------------------------------------------------------------
// Head (fp32): one block per (w,b) slot.
// ---------------------------------------------------------------------------
__global__ __launch_bounds__(256)
void head_kernel(const float* __restrict__ x, const float* __restrict__ noise,
                 const float* __restrict__ pw1, const float* __restrict__ pb1,
                 const float* __restrict__ pw2, const float* __restrict__ pb2,
                 const float* __restrict__ ew1, const float* __restrict__ eb1,
                 const float* __restrict__ ew2, const float* __restrict__ eb2,
                 float* __restrict__ out)
{
  int idx = blockIdx.x;
  int b = idx & 127, w = idx >> 7;
  int tid = threadIdx.x;
  __shared__ float slot[192];
  __shared__ float ph[256];
  __shared__ float eh[128];
  if (tid < 192)
    slot[tid] = x[((size_t)b * S_ + (S_ - 1)) * D_ + tid]
              + noise[((size_t)w * B_ + b) * D_ + tid] * 0.1f;
  __syncthreads();
  {
    const float4* wr = (const float4*)(pw1 + (size_t)tid * D_);
    const float4* sp = (const float4*)slot;
    float a = pb1[tid];
    #pragma unroll 12
    for (int k = 0; k < 48; ++k) {
      float4 wv = wr[k], sv = sp[k];
      a += wv.x*sv.x + wv.y*sv.y + wv.z*sv.z + wv.w*sv.w;
    }
    ph[tid] = fmaxf(a, 0.f);
  }
  if (tid < 128) {
    const float4* wr = (const float4*)(ew1 + (size_t)tid * D_);
    const float4* sp = (const float4*)slot;
    float a = eb1[tid];
    #pragma unroll 12
    for (int k = 0; k < 48; ++k) {
      float4 wv = wr[k], sv = sp[k];
      a += wv.x*sv.x + wv.y*sv.y + wv.z*sv.z + wv.w*sv.w;
    }
    eh[tid] = fmaxf(a, 0.f);
  }
  __syncthreads();
  if (tid < 4) {
    float a = pb2[tid];
    const float4* wr = (const float4*)(pw2 + tid * 256);
    const float4* pp = (const float4*)ph;
    for (int k = 0; k < 64; ++k) {
      float4 wv = wr[k], pv = pp[k];
      a += wv.x*pv.x + wv.y*pv.y + wv.z*pv.z + wv.w*pv.w;
    }
    out[((size_t)b * W_ + w) * 4 + tid] = a;
  }
  if (tid == 4) {
    float a = eb2[0];
    const float4* wr = (const float4*)ew2;
    const float4* pp = (const float4*)eh;
    for (int k = 0; k < 32; ++k) {
      float4 wv = wr[k], pv = pp[k];
      a += wv.x*pv.x + wv.y*pv.y + wv.z*pv.z + wv.w*pv.w;
    }
    out[(size_t)B_ * W_ * 4 + (size_t)b * W_ + w] = 1.f / (1.f + expf(-a));
  }
}

// ---------------------------------------------------------------------------
extern "C" void kernel_launch(void* const* d_in, const int* in_sizes, int n_in,
                              void* d_out, int out_size, void* d_ws, size_t ws_size,
                              hipStream_t stream)
{
  const int*   title_idx       = (const int*)  d_in[0];
  const int*   class_idx       = (const int*)  d_in[1];
  const int*   process_idx     = (const int*)  d_in[2];
  const int*   activity_type   = (const int*)  d_in[3];
  const float* mouse_pos       = (const float*)d_in[4];
  const float* rect            = (const float*)d_in[5];
  const float* flags           = (const float*)d_in[6];
  const float* keyboard_active = (const float*)d_in[7];
  const float* window_mask     = (const float*)d_in[8];
  const float* noise           = (const float*)d_in[9];
  const float* title_emb       = (const float*)d_in[10];
  const float* class_emb       = (const float*)d_in[11];
  const float* process_emb     = (const float*)d_in[12];
  const float* spatial_w1      = (const float*)d_in[13];
  const float* spatial_b1      = (const float*)d_in[14];
  const float* spatial_w2      = (const float*)d_in[15];
  const float* spatial_b2      = (const float*)d_in[16];
  const float* wfuse_w         = (const float*)d_in[17];
  const float* wfuse_b         = (const float*)d_in[18];
  const float* mouse_w1        = (const float*)d_in[19];
  const float* mouse_b1        = (const float*)d_in[20];
  const float* mouse_w2        = (const float*)d_in[21];
  const float* mouse_b2        = (const float*)d_in[22];
  const float* act_emb         = (const float*)d_in[23];
  const float* kbd_w           = (const float*)d_in[24];
  const float* kbd_b           = (const float*)d_in[25];
  const float* afuse_w         = (const float*)d_in[26];
  const float* afuse_b         = (const float*)d_in[27];
  const float* qkv_w           = (const float*)d_in[28];
  const float* qkv_b           = (const float*)d_in[29];
  const float* out_w           = (const float*)d_in[30];
  const float* out_b           = (const float*)d_in[31];
  const float* ff1_w           = (const float*)d_in[32];
  const float* ff1_b           = (const float*)d_in[33];
  const float* ff2_w           = (const float*)d_in[34];
  const float* ff2_b           = (const float*)d_in[35];
  const float* ln1_g           = (const float*)d_in[36];
  const float* ln1_b           = (const float*)d_in[37];
  const float* ln2_g           = (const float*)d_in[38];
  const float* ln2_b           = (const float*)d_in[39];
  const float* proj_w1         = (const float*)d_in[40];
  const float* proj_b1         = (const float*)d_in[41];
  const float* proj_w2         = (const float*)d_in[42];
  const float* proj_b2         = (const float*)d_in[43];
  const float* ex_w1           = (const float*)d_in[44];
  const float* ex_b1           = (const float*)d_in[45];
  const float* ex_w2           = (const float*)d_in[46];
  const float* ex_b2           = (const float*)d_in[47];

  float* out = (float*)d_out;

  // workspace layout
  float* x    = (float*)d_ws;                        // 12800*192 f32
  float* tmp  = x + (size_t)BS_ * D_;                // 12800*192 f32
  __hip_bfloat16* xb    = (__hip_bfloat16*)(tmp + (size_t)BS_ * D_);  // 12800*192
  __hip_bfloat16* qkvb  = xb    + (size_t)BS_ * D_;       // 12800*576
  __hip_bfloat16* attb  = qkvb  + (size_t)BS_ * THREED_;  // 12800*192
  __hip_bfloat16* ffb   = attb  + (size_t)BS_ * D_;       // 12800*256
  __hip_bfloat16* wqb   = ffb   + (size_t)BS_ * DFF_;     // 6*576*192
  __hip_bfloat16* wob   = wqb   + (size_t)L_ * THREED_ * D_;  // 6*192*192
  __hip_bfloat16* wf1b  = wob   + (size_t)L_ * D_ * D_;       // 6*256*192
  __hip_bfloat16* wf2b  = wf1b  + (size_t)L_ * DFF_ * D_;     // 6*192*256
  (void)ws_size; (void)n_in; (void)in_sizes; (void)out_size;

  // weight conversion (per call; inputs re-pristined by harness each launch)
  convert_kernel<<<(L_ * THREED_ * D_) / (256 * 8), 256, 0, stream>>>(qkv_w, wqb);
  convert_kernel<<<(L_ * D_ * D_) / (256 * 8), 256, 0, stream>>>(out_w, wob);
  convert_kernel<<<(L_ * DFF_ * D_) / (256 * 8), 256, 0, stream>>>(ff1_w, wf1b);
  convert_kernel<<<(L_ * D_ * DFF_) / (256 * 8), 256, 0, stream>>>(ff2_w, wf2b);

  // 1. fused encoder (writes x fp32 + xb bf16)
  encode_fused_kernel<<<BS_ / 4, 256, 0, stream>>>(
      title_idx, class_idx, process_idx, activity_type, mouse_pos, rect, flags,
      keyboard_active, window_mask, title_emb, class_emb, process_emb,
      spatial_w1, spatial_b1, spatial_w2, spatial_b2, wfuse_w, wfuse_b,
      mouse_w1, mouse_b1, mouse_w2, mouse_b2, act_emb, kbd_w, kbd_b,
      afuse_w, afuse_b, x, xb);

  // 2. transformer layers (MFMA GEMMs)
  for (int l = 0; l < L_; ++l) {
    mfma_gemm_kernel<false, false, true><<<dim3(THREED_ / 64, BS_ / 128), 128, 0, stream>>>(
        xb, wqb + (size_t)l * THREED_ * D_, qkv_b + (size_t)l * THREED_,
        nullptr, qkvb, THREED_, D_);
    attn_kernel<<<B_ * H_, 256, 0, stream>>>(qkvb, attb);
    mfma_gemm_kernel<false, true, false><<<dim3(D_ / 64, BS_ / 128), 128, 0, stream>>>(
        attb, wob + (size_t)l * D_ * D_, out_b + (size_t)l * D_,
        tmp, nullptr, D_, D_);
    residual_ln_kernel<<<BS_ / 4, 256, 0, stream>>>(
        x, tmp, ln1_g + (size_t)l * D_, ln1_b + (size_t)l * D_, xb);
    mfma_gemm_kernel<true, false, true><<<dim3(DFF_ / 64, BS_ / 128), 128, 0, stream>>>(
        xb, wf1b + (size_t)l * DFF_ * D_, ff1_b + (size_t)l * DFF_,
        nullptr, ffb, DFF_, D_);
    mfma_gemm_kernel<false, true, false><<<dim3(D_ / 64, BS_ / 128), 128, 0, stream>>>(
        ffb, wf2b + (size_t)l * D_ * DFF_, ff2_b + (size_t)l * D_,
        tmp, nullptr, D_, DFF_);
    residual_ln_kernel<<<BS_ / 4, 256, 0, stream>>>(
        x, tmp, ln2_g + (size_t)l * D_, ln2_b + (size_t)l * D_, xb);
  }

  // 3. head
  head_kernel<<<W_ * B_, 256, 0, stream>>>(
      x, noise, proj_w1, proj_b1, proj_w2, proj_b2,
      ex_w1, ex_b1, ex_w2, ex_b2, out);
}